// Round 3
// baseline (288.696 us; speedup 1.0000x reference)
//
#include <hip/hip_runtime.h>
#include <stdint.h>
#include <stddef.h>

// ---------------------------------------------------------------------------
// MultiHeadAttention: B=8 S=1024 D=1024 H=16 HD=64  (fp32 in/out, bf16 MFMA)
// ---------------------------------------------------------------------------

typedef short bf16x8 __attribute__((ext_vector_type(8)));   // 8 bf16 = 4 VGPR (guide §3)
typedef float f32x4  __attribute__((ext_vector_type(4)));
typedef unsigned short u16x8 __attribute__((ext_vector_type(8)));
typedef unsigned short u16x4 __attribute__((ext_vector_type(4)));

#define MFMA16 __builtin_amdgcn_mfma_f32_16x16x32_bf16

typedef const void __attribute__((address_space(1)))* gas1_t;
typedef void __attribute__((address_space(3)))* las3_t;

static __device__ __forceinline__ void gload16(const void* g, void* l) {
  // async global->LDS, 16B/lane, dest = wave-uniform base + lane*16
  __builtin_amdgcn_global_load_lds((gas1_t)g, (las3_t)l, 16, 0, 0);
}

static __device__ __forceinline__ unsigned short f2bf(float f) {
  union { float f; unsigned int u; } v; v.f = f;
  unsigned int r = v.u + 0x7fffu + ((v.u >> 16) & 1u);   // RNE
  return (unsigned short)(r >> 16);
}

// ---------------- cast inputs to bf16 ----------------
// x: 8388608 f32, Wq/Wk/Wv: 1048576 each, Wo: 1048576. total vec4 tasks 3145728.
__global__ __launch_bounds__(256) void cast_all(
    const float* __restrict__ x, const float* __restrict__ Wq,
    const float* __restrict__ Wk, const float* __restrict__ Wv,
    const float* __restrict__ Wo,
    unsigned short* __restrict__ xb, unsigned short* __restrict__ wqkv,
    unsigned short* __restrict__ wob) {
  int base = (blockIdx.x * 256 + threadIdx.x) * 4;
  const float* s; unsigned short* d;
  if (base < 8388608) { s = x + base; d = xb + base; }
  else if (base < 11534336) {
    int o = base - 8388608; int wi = o >> 20;
    const float* w = (wi == 0) ? Wq : (wi == 1) ? Wk : Wv;
    s = w + (o & 1048575); d = wqkv + o;
  } else {
    int o = base - 11534336; s = Wo + o; d = wob + o;
  }
  float4 f = *(const float4*)s;
  u16x4 r; r[0] = f2bf(f.x); r[1] = f2bf(f.y); r[2] = f2bf(f.z); r[3] = f2bf(f.w);
  *(u16x4*)d = r;
}

// ---------------- 128x128 bf16 GEMM, C = A * B^T, K=1024 ----------------
// A [M,1024] row-major bf16, Bm [N,1024] row-major bf16 (= B^T layout).
// EPI 0: scatter to Q/K/V [B,H,S,64] bf16 with bias (+0.125 scale on Q)
// EPI 1: f32 out + bias -> Cf
// NOTE: robust to MFMA a/b-frag k-permutation (applied identically to both
// operands -> cancels in the dot product). Only the C/D mapping
// (col=lane&15, row=(lane>>4)*4+reg, m89-verified) is load-bearing.
template <int EPI>
__global__ __launch_bounds__(256) void gemm128(
    const unsigned short* __restrict__ A, const unsigned short* __restrict__ Bm,
    float* __restrict__ Cf, const float* __restrict__ bO,
    unsigned short* __restrict__ Qo, unsigned short* __restrict__ Ko,
    unsigned short* __restrict__ Vo,
    const float* __restrict__ bq, const float* __restrict__ bk,
    const float* __restrict__ bv) {
  __shared__ __align__(16) char sm[32768];
  char* As = sm; char* Bs = sm + 16384;           // [128][64] bf16 each, XOR-swizzled
  const int tid = threadIdx.x, lane = tid & 63, w = tid >> 6;
  const int wr = w >> 1, wc = w & 1;
  const int brow = blockIdx.y * 128, bcol = blockIdx.x * 128;
  const int l15 = lane & 15, g = lane >> 4;
  f32x4 acc[4][4] = {};
  for (int ks = 0; ks < 16; ++ks) {
    __syncthreads();
#pragma unroll
    for (int j = 0; j < 4; ++j) {
      int p = (w * 4 + j) * 1024 + lane * 16;     // physical LDS byte this lane fills
      int row = p >> 7;                           // 128B per row
      int cl = (lane & 7) ^ (row & 7);            // pre-swizzled source chunk (rule #21)
      gload16(A + (size_t)(brow + row) * 1024 + ks * 64 + cl * 8,
              As + (w * 4 + j) * 1024);
      gload16(Bm + (size_t)(bcol + row) * 1024 + ks * 64 + cl * 8,
              Bs + (w * 4 + j) * 1024);
    }
    asm volatile("s_waitcnt vmcnt(0)" ::: "memory");
    __syncthreads();
#pragma unroll
    for (int kk = 0; kk < 2; ++kk) {
      bf16x8 af[4], bfr[4];
#pragma unroll
      for (int mi = 0; mi < 4; ++mi) {
        int row = wr * 64 + mi * 16 + l15;
        int off = (row * 128 + kk * 64 + g * 16) ^ ((row & 7) << 4);
        af[mi] = *(const bf16x8*)(As + off);
      }
#pragma unroll
      for (int ni = 0; ni < 4; ++ni) {
        int row = wc * 64 + ni * 16 + l15;
        int off = (row * 128 + kk * 64 + g * 16) ^ ((row & 7) << 4);
        bfr[ni] = *(const bf16x8*)(Bs + off);
      }
#pragma unroll
      for (int mi = 0; mi < 4; ++mi)
#pragma unroll
        for (int ni = 0; ni < 4; ++ni)
          acc[mi][ni] = MFMA16(af[mi], bfr[ni], acc[mi][ni], 0, 0, 0);
    }
  }
  // epilogue: C/D frag mapping col=lane&15, row=(lane>>4)*4+reg (m89-verified)
  if constexpr (EPI == 0) {
    const int b = brow >> 10;                     // 128 | 1024 -> constant per block
#pragma unroll
    for (int ni = 0; ni < 4; ++ni) {
      int n = bcol + wc * 64 + ni * 16 + l15;
      int t = n >> 10, nh = n & 1023;
      int h = nh >> 6, hd = nh & 63;
      const float* bias = (t == 0) ? bq : (t == 1) ? bk : bv;
      float bb = bias[nh];
      float scale = (t == 0) ? 0.125f : 1.0f;     // fold 1/sqrt(HD) into Q
      unsigned short* dst = (t == 0) ? Qo : (t == 1) ? Ko : Vo;
      size_t basei = ((size_t)(b * 16 + h) * 1024) * 64 + hd;
#pragma unroll
      for (int mi = 0; mi < 4; ++mi)
#pragma unroll
        for (int r = 0; r < 4; ++r) {
          int m = brow + wr * 64 + mi * 16 + g * 4 + r;
          int srow = m & 1023;
          dst[basei + (size_t)srow * 64] = f2bf((acc[mi][ni][r] + bb) * scale);
        }
    }
  } else {
#pragma unroll
    for (int ni = 0; ni < 4; ++ni) {
      int n = bcol + wc * 64 + ni * 16 + l15;
      float bb = bO[n];
#pragma unroll
      for (int mi = 0; mi < 4; ++mi)
#pragma unroll
        for (int r = 0; r < 4; ++r) {
          int m = brow + wr * 64 + mi * 16 + g * 4 + r;
          Cf[(size_t)m * 1024 + n] = acc[mi][ni][r] + bb;
        }
    }
  }
}

// ---------------- fused flash attention ----------------
// grid (qtile=8, h=16, b=8), 256 threads = 4 waves; each wave owns 32 q-rows.
// Swapped scores: S^T = mfma(Kfrag, Qfrag) -> lane holds col q, rows k.
__global__ __launch_bounds__(256) void attn_fused(
    const unsigned short* __restrict__ Qb, const unsigned short* __restrict__ Kb,
    const unsigned short* __restrict__ Vb, unsigned short* __restrict__ Cc) {
  __shared__ __align__(16) char sm[52224];
  char* Qs = sm;                 // [128][64] bf16, swizzled      (16384 B)
  char* Ks = sm + 16384;         // [64][64]  bf16, swizzled      ( 8192 B)
  char* Vt = sm + 24576;         // [64 d][72 s] bf16, padded     ( 9216 B)
  const int tid = threadIdx.x, lane = tid & 63, w = tid >> 6;
  char* Ps = sm + 33792 + w * 4608;  // per-wave P [32 q][72 s] bf16
  const int l15 = lane & 15, g = lane >> 4;
  const int qt = blockIdx.x, h = blockIdx.y, b = blockIdx.z;
  const size_t hb = (size_t)(b * 16 + h) * (1024 * 64);

  // stage Q tile once (pre-swizzled source, linear LDS dest)
#pragma unroll
  for (int j = 0; j < 4; ++j) {
    int p = (w * 4 + j) * 1024 + lane * 16;
    int row = p >> 7;
    int cl = (lane & 7) ^ (row & 7);
    gload16(Qb + hb + (size_t)(qt * 128 + row) * 64 + cl * 8, Qs + (w * 4 + j) * 1024);
  }

  f32x4 acc_o[2][4] = {};
  float m_run[2] = {-1e30f, -1e30f};
  float l_run[2] = {0.f, 0.f};

  for (int c = 0; c < 16; ++c) {
    __syncthreads();                              // prev chunk's reads done
#pragma unroll
    for (int j = 0; j < 2; ++j) {                 // K chunk [64][64]
      int p = (w * 2 + j) * 1024 + lane * 16;
      int row = p >> 7;
      int cl = (lane & 7) ^ (row & 7);
      gload16(Kb + hb + (size_t)(c * 64 + row) * 64 + cl * 8, Ks + (w * 2 + j) * 1024);
    }
#pragma unroll
    for (int i = 0; i < 2; ++i) {                 // V chunk transposed into Vt[d][s]
      int idx = tid + i * 256;
      int srow = idx >> 3, oct = idx & 7;
      u16x8 vv = *(const u16x8*)(Vb + hb + (size_t)(c * 64 + srow) * 64 + oct * 8);
#pragma unroll
      for (int jj = 0; jj < 8; ++jj)
        *(unsigned short*)(Vt + ((oct * 8 + jj) * 72 + srow) * 2) = vv[jj];
    }
    asm volatile("s_waitcnt vmcnt(0)" ::: "memory");
    __syncthreads();

    // S^T [64 k][32 q] per wave: frag mi over k (4), ni over q (2)
    f32x4 st[4][2] = {};
#pragma unroll
    for (int kk = 0; kk < 2; ++kk) {
      bf16x8 ka[4], qf[2];
#pragma unroll
      for (int mi = 0; mi < 4; ++mi) {
        int row = mi * 16 + l15;
        int off = (row * 128 + kk * 64 + g * 16) ^ ((row & 7) << 4);
        ka[mi] = *(const bf16x8*)(Ks + off);
      }
#pragma unroll
      for (int ni = 0; ni < 2; ++ni) {
        int row = w * 32 + ni * 16 + l15;
        int off = (row * 128 + kk * 64 + g * 16) ^ ((row & 7) << 4);
        qf[ni] = *(const bf16x8*)(Qs + off);
      }
#pragma unroll
      for (int mi = 0; mi < 4; ++mi)
#pragma unroll
        for (int ni = 0; ni < 2; ++ni)
          st[mi][ni] = MFMA16(ka[mi], qf[ni], st[mi][ni], 0, 0, 0);
    }

    // online softmax: lane holds 16 of 64 k-values for q = ni*16+l15
    float corr_s[2];
#pragma unroll
    for (int ni = 0; ni < 2; ++ni) {
      float mx = -1e30f;
#pragma unroll
      for (int mi = 0; mi < 4; ++mi)
#pragma unroll
        for (int r = 0; r < 4; ++r) mx = fmaxf(mx, st[mi][ni][r]);
      mx = fmaxf(mx, __shfl_xor(mx, 16));
      mx = fmaxf(mx, __shfl_xor(mx, 32));
      float mn = fmaxf(m_run[ni], mx);
      float corr = __expf(m_run[ni] - mn);
      float sum = 0.f;
#pragma unroll
      for (int mi = 0; mi < 4; ++mi) {
        u16x4 pk;
#pragma unroll
        for (int r = 0; r < 4; ++r) {
          float e = __expf(st[mi][ni][r] - mn);
          sum += e;
          pk[r] = f2bf(e);
        }
        // P[q][s]: s = mi*16+g*4+r contiguous -> one ds_write_b64
        *(u16x4*)(Ps + ((ni * 16 + l15) * 72 + mi * 16 + g * 4) * 2) = pk;
      }
      sum += __shfl_xor(sum, 16);
      sum += __shfl_xor(sum, 32);
      l_run[ni] = l_run[ni] * corr + sum;
      m_run[ni] = mn;
      corr_s[ni] = corr;
    }

    // rescale O accumulators (q of acc_o reg r = mi*16 + g*4 + r)
#pragma unroll
    for (int mi = 0; mi < 2; ++mi) {
      float cr[4];
#pragma unroll
      for (int r = 0; r < 4; ++r)
        cr[r] = __shfl(corr_s[mi], (lane & 48) + g * 4 + r);
#pragma unroll
      for (int nd = 0; nd < 4; ++nd)
#pragma unroll
        for (int r = 0; r < 4; ++r)
          acc_o[mi][nd][r] *= cr[r];
    }

    // PV: O[q][d] += P[q][s] * Vt[d][s]
#pragma unroll
    for (int kk = 0; kk < 2; ++kk) {
      bf16x8 pa[2], vf[4];
#pragma unroll
      for (int mi = 0; mi < 2; ++mi)
        pa[mi] = *(const bf16x8*)(Ps + (mi * 16 + l15) * 144 + kk * 64 + g * 16);
#pragma unroll
      for (int nd = 0; nd < 4; ++nd)
        vf[nd] = *(const bf16x8*)(Vt + (nd * 16 + l15) * 144 + kk * 64 + g * 16);
#pragma unroll
      for (int mi = 0; mi < 2; ++mi)
#pragma unroll
        for (int nd = 0; nd < 4; ++nd)
          acc_o[mi][nd] = MFMA16(pa[mi], vf[nd], acc_o[mi][nd], 0, 0, 0);
    }
  }

  // finalize: divide by l, write concat [B,S,D] bf16
  float invl[2] = {1.f / l_run[0], 1.f / l_run[1]};
#pragma unroll
  for (int mi = 0; mi < 2; ++mi) {
    float iv[4];
#pragma unroll
    for (int r = 0; r < 4; ++r)
      iv[r] = __shfl(invl[mi], (lane & 48) + g * 4 + r);
#pragma unroll
    for (int nd = 0; nd < 4; ++nd)
#pragma unroll
      for (int r = 0; r < 4; ++r) {
        int q = qt * 128 + w * 32 + mi * 16 + g * 4 + r;
        int col = h * 64 + nd * 16 + l15;
        Cc[(size_t)(b * 1024 + q) * 1024 + col] = f2bf(acc_o[mi][nd][r] * iv[r]);
      }
  }
}

// ---------------- launch ----------------
extern "C" void kernel_launch(void* const* d_in, const int* in_sizes, int n_in,
                              void* d_out, int out_size, void* d_ws, size_t ws_size,
                              hipStream_t stream) {
  const float* x  = (const float*)d_in[0];
  const float* Wq = (const float*)d_in[1];
  const float* Wk = (const float*)d_in[2];
  const float* Wv = (const float*)d_in[3];
  const float* bq = (const float*)d_in[4];
  const float* bk = (const float*)d_in[5];
  const float* bv = (const float*)d_in[6];
  const float* Wo = (const float*)d_in[7];
  const float* bo = (const float*)d_in[8];

  char* ws = (char*)d_ws;
  unsigned short* xb   = (unsigned short*)(ws);               // 16 MB (dead after gemm<0>)
  unsigned short* wqkv = (unsigned short*)(ws + 16777216);    //  6 MB [3][1024][1024]
  unsigned short* wob  = (unsigned short*)(ws + 23068672);    //  2 MB
  unsigned short* Qb   = (unsigned short*)(ws + 25165824);    // 16 MB [B,H,S,64]
  unsigned short* Kb   = (unsigned short*)(ws + 41943040);    // 16 MB
  unsigned short* Vb   = (unsigned short*)(ws + 58720256);    // 16 MB
  unsigned short* Cc   = xb;   // alias: xb dead after gemm<0>; peak ws = 75.5 MB

  cast_all<<<dim3(12288), dim3(256), 0, stream>>>(x, Wq, Wk, Wv, Wo, xb, wqkv, wob);
  gemm128<0><<<dim3(24, 64), dim3(256), 0, stream>>>(
      xb, wqkv, nullptr, nullptr, Qb, Kb, Vb, bq, bk, bv);
  attn_fused<<<dim3(8, 16, 8), dim3(256), 0, stream>>>(Qb, Kb, Vb, Cc);
  gemm128<1><<<dim3(8, 64), dim3(256), 0, stream>>>(
      Cc, wob, (float*)d_out, bo, nullptr, nullptr, nullptr, nullptr, nullptr, nullptr);
}

// Round 5
// 255.682 us; speedup vs baseline: 1.1291x; 1.1291x over previous
//
#include <hip/hip_runtime.h>
#include <stdint.h>
#include <stddef.h>

// ---------------------------------------------------------------------------
// MultiHeadAttention: B=8 S=1024 D=1024 H=16 HD=64  (fp32 in/out, bf16 MFMA)
// R4: attn overhaul — V^T global layout, O^T accumulation (shuffle-free
// softmax rescale), Q in registers, double-buffered K/V^T staging with
// early-issue pipeline (1 barrier/chunk), head->XCD locality swizzle.
// ---------------------------------------------------------------------------

typedef short bf16x8 __attribute__((ext_vector_type(8)));   // 8 bf16 = 4 VGPR
typedef float f32x4  __attribute__((ext_vector_type(4)));
typedef unsigned short u16x8 __attribute__((ext_vector_type(8)));
typedef unsigned short u16x4 __attribute__((ext_vector_type(4)));

#define MFMA16 __builtin_amdgcn_mfma_f32_16x16x32_bf16

typedef const void __attribute__((address_space(1)))* gas1_t;
typedef void __attribute__((address_space(3)))* las3_t;

static __device__ __forceinline__ void gload16(const void* g, void* l) {
  // async global->LDS, 16B/lane, dest = wave-uniform base + lane*16
  __builtin_amdgcn_global_load_lds((gas1_t)g, (las3_t)l, 16, 0, 0);
}

static __device__ __forceinline__ unsigned short f2bf(float f) {
  union { float f; unsigned int u; } v; v.f = f;
  unsigned int r = v.u + 0x7fffu + ((v.u >> 16) & 1u);   // RNE
  return (unsigned short)(r >> 16);
}

// ---------------- cast inputs to bf16 ----------------
__global__ __launch_bounds__(256) void cast_all(
    const float* __restrict__ x, const float* __restrict__ Wq,
    const float* __restrict__ Wk, const float* __restrict__ Wv,
    const float* __restrict__ Wo,
    unsigned short* __restrict__ xb, unsigned short* __restrict__ wqkv,
    unsigned short* __restrict__ wob) {
  int base = (blockIdx.x * 256 + threadIdx.x) * 4;
  const float* s; unsigned short* d;
  if (base < 8388608) { s = x + base; d = xb + base; }
  else if (base < 11534336) {
    int o = base - 8388608; int wi = o >> 20;
    const float* w = (wi == 0) ? Wq : (wi == 1) ? Wk : Wv;
    s = w + (o & 1048575); d = wqkv + o;
  } else {
    int o = base - 11534336; s = Wo + o; d = wob + o;
  }
  float4 f = *(const float4*)s;
  u16x4 r; r[0] = f2bf(f.x); r[1] = f2bf(f.y); r[2] = f2bf(f.z); r[3] = f2bf(f.w);
  *(u16x4*)d = r;
}

// ---------------- 128x128 bf16 GEMM, C = A * B^T, K=1024 ----------------
// EPI 0: scatter Q/K -> [B,H,S,64] bf16 (+bias, Q scaled 0.125); V -> V^T
//        [B*H, 64 hd, 1024 s] bf16 (+bias) with packed u16x4 stores.
// EPI 1: f32 out + bias -> Cf
template <int EPI>
__global__ __launch_bounds__(256) void gemm128(
    const unsigned short* __restrict__ A, const unsigned short* __restrict__ Bm,
    float* __restrict__ Cf, const float* __restrict__ bO,
    unsigned short* __restrict__ Qo, unsigned short* __restrict__ Ko,
    unsigned short* __restrict__ Vo,
    const float* __restrict__ bq, const float* __restrict__ bk,
    const float* __restrict__ bv) {
  __shared__ __align__(16) char sm[32768];
  char* As = sm; char* Bs = sm + 16384;           // [128][64] bf16 each, XOR-swizzled
  const int tid = threadIdx.x, lane = tid & 63, w = tid >> 6;
  const int wr = w >> 1, wc = w & 1;
  const int brow = blockIdx.y * 128, bcol = blockIdx.x * 128;
  const int l15 = lane & 15, g = lane >> 4;
  f32x4 acc[4][4] = {};
  for (int ks = 0; ks < 16; ++ks) {
    __syncthreads();
#pragma unroll
    for (int j = 0; j < 4; ++j) {
      int p = (w * 4 + j) * 1024 + lane * 16;     // physical LDS byte this lane fills
      int row = p >> 7;                           // 128B per row
      int cl = (lane & 7) ^ (row & 7);            // pre-swizzled source chunk (rule #21)
      gload16(A + (size_t)(brow + row) * 1024 + ks * 64 + cl * 8,
              As + (w * 4 + j) * 1024);
      gload16(Bm + (size_t)(bcol + row) * 1024 + ks * 64 + cl * 8,
              Bs + (w * 4 + j) * 1024);
    }
    asm volatile("s_waitcnt vmcnt(0)" ::: "memory");
    __syncthreads();
#pragma unroll
    for (int kk = 0; kk < 2; ++kk) {
      bf16x8 af[4], bfr[4];
#pragma unroll
      for (int mi = 0; mi < 4; ++mi) {
        int row = wr * 64 + mi * 16 + l15;
        int off = (row * 128 + kk * 64 + g * 16) ^ ((row & 7) << 4);
        af[mi] = *(const bf16x8*)(As + off);
      }
#pragma unroll
      for (int ni = 0; ni < 4; ++ni) {
        int row = wc * 64 + ni * 16 + l15;
        int off = (row * 128 + kk * 64 + g * 16) ^ ((row & 7) << 4);
        bfr[ni] = *(const bf16x8*)(Bs + off);
      }
#pragma unroll
      for (int mi = 0; mi < 4; ++mi)
#pragma unroll
        for (int ni = 0; ni < 4; ++ni)
          acc[mi][ni] = MFMA16(af[mi], bfr[ni], acc[mi][ni], 0, 0, 0);
    }
  }
  // epilogue: C/D frag mapping col=lane&15, row=(lane>>4)*4+reg (m89-verified)
  if constexpr (EPI == 0) {
    const int b = brow >> 10;                     // 128 | 1024 -> constant per block
#pragma unroll
    for (int ni = 0; ni < 4; ++ni) {
      int n = bcol + wc * 64 + ni * 16 + l15;
      int t = n >> 10, nh = n & 1023;             // t wave-uniform (16-wide n span)
      int h = nh >> 6, hd = nh & 63;
      const float* bias = (t == 0) ? bq : (t == 1) ? bk : bv;
      float bb = bias[nh];
      if (t == 2) {
        // V^T: [(b*16+h)*64 + hd][1024 s], 4 consecutive s -> one 8B store
        size_t vtb = ((size_t)(b * 16 + h) * 64 + hd) * 1024;
#pragma unroll
        for (int mi = 0; mi < 4; ++mi) {
          int m0 = brow + wr * 64 + mi * 16 + g * 4;
          int srow0 = m0 & 1023;
          u16x4 vv;
#pragma unroll
          for (int r = 0; r < 4; ++r) vv[r] = f2bf(acc[mi][ni][r] + bb);
          *(u16x4*)(Vo + vtb + srow0) = vv;
        }
      } else {
        float scale = (t == 0) ? 0.125f : 1.0f;   // fold 1/sqrt(HD) into Q
        unsigned short* dst = (t == 0) ? Qo : Ko;
        size_t basei = ((size_t)(b * 16 + h) * 1024) * 64 + hd;
#pragma unroll
        for (int mi = 0; mi < 4; ++mi)
#pragma unroll
          for (int r = 0; r < 4; ++r) {
            int m = brow + wr * 64 + mi * 16 + g * 4 + r;
            int srow = m & 1023;
            dst[basei + (size_t)srow * 64] = f2bf((acc[mi][ni][r] + bb) * scale);
          }
      }
    }
  } else {
#pragma unroll
    for (int ni = 0; ni < 4; ++ni) {
      int n = bcol + wc * 64 + ni * 16 + l15;
      float bb = bO[n];
#pragma unroll
      for (int mi = 0; mi < 4; ++mi)
#pragma unroll
        for (int r = 0; r < 4; ++r) {
          int m = brow + wr * 64 + mi * 16 + g * 4 + r;
          Cf[(size_t)m * 1024 + n] = acc[mi][ni][r] + bb;
        }
    }
  }
}

// ---------------- fused flash attention (O^T orientation) ----------------
// 1-D grid 1024: id = qt*128 + bh  ->  all 8 q-tiles of head bh share id%8
// (same XCD L2 under round-robin dispatch). 256 thr = 4 waves, 32 q/wave.
// S^T = mfma(K, Q): lane holds col q = ni*16+l15, rows k.
// O^T = mfma(V^T, P): col q again -> corr/invl apply per-lane, NO shuffles.
__global__ __launch_bounds__(256, 3) void attn_fused(
    const unsigned short* __restrict__ Qb, const unsigned short* __restrict__ Kb,
    const unsigned short* __restrict__ VtG, unsigned short* __restrict__ Cc) {
  __shared__ __align__(16) char sm[49152];
  char* Ks = sm;                    // 2 x [64 s][64 d] bf16, XOR-swizzled (16K)
  char* Vt = sm + 16384;            // 2 x [64 d][64 s] bf16, XOR-swizzled (16K)
  const int tid = threadIdx.x, lane = tid & 63, w = tid >> 6;
  char* Ps = sm + 32768 + w * 4096; // per-wave [32 q][64 s] bf16, XOR-swizzled
  const int l15 = lane & 15, g = lane >> 4;
  const int id = blockIdx.x;
  const int qt = id >> 7, bh = id & 127;          // head-locality decode
  const size_t hb = (size_t)bh * (1024 * 64);

  // Q fragments straight to registers (B-operand rows q, d-contiguous)
  bf16x8 qreg[2][2];                               // [kk][ni]
#pragma unroll
  for (int kk = 0; kk < 2; ++kk)
#pragma unroll
    for (int ni = 0; ni < 2; ++ni) {
      int q = qt * 128 + w * 32 + ni * 16 + l15;
      qreg[kk][ni] = *(const bf16x8*)(Qb + hb + (size_t)q * 64 + kk * 32 + g * 8);
    }

  auto stage = [&](int c, int buf) {
#pragma unroll
    for (int j = 0; j < 2; ++j) {
      int p = (w * 2 + j) * 1024 + lane * 16;     // linear LDS byte this lane fills
      int row = p >> 7;
      int cl = (lane & 7) ^ (row & 7);            // pre-swizzled source (rule #21)
      gload16(Kb + hb + (size_t)(c * 64 + row) * 64 + cl * 8,
              Ks + buf * 8192 + (w * 2 + j) * 1024);
      gload16(VtG + hb + (size_t)row * 1024 + c * 64 + cl * 8,
              Vt + buf * 8192 + (w * 2 + j) * 1024);
    }
  };

  stage(0, 0);
  asm volatile("s_waitcnt vmcnt(0)" ::: "memory");
  __syncthreads();

  f32x4 acc[4][2] = {};                            // O^T [nd: d-frag][ni: q-frag]
  float m_run[2] = {-1e30f, -1e30f};
  float l_run[2] = {0.f, 0.f};

  for (int c = 0; c < 16; ++c) {
    const int cur = c & 1;
    if (c < 15) stage(c + 1, cur ^ 1);             // early issue; drains at bottom
    const char* Kc = Ks + cur * 8192;
    const char* Vc = Vt + cur * 8192;

    // S^T[k][q] = K · Q^T
    f32x4 st[4][2] = {};
#pragma unroll
    for (int kk = 0; kk < 2; ++kk) {
      bf16x8 ka[4];
#pragma unroll
      for (int mi = 0; mi < 4; ++mi) {
        int row = mi * 16 + l15;
        int off = (row * 128 + kk * 64 + g * 16) ^ ((row & 7) << 4);
        ka[mi] = *(const bf16x8*)(Kc + off);
      }
#pragma unroll
      for (int mi = 0; mi < 4; ++mi)
#pragma unroll
        for (int ni = 0; ni < 2; ++ni)
          st[mi][ni] = MFMA16(ka[mi], qreg[kk][ni], st[mi][ni], 0, 0, 0);
    }

    // online softmax: lane holds 16 of 64 k for q = ni*16+l15 (4 g-lanes/q)
    float corr_s[2];
#pragma unroll
    for (int ni = 0; ni < 2; ++ni) {
      float mx = -1e30f;
#pragma unroll
      for (int mi = 0; mi < 4; ++mi)
#pragma unroll
        for (int r = 0; r < 4; ++r) mx = fmaxf(mx, st[mi][ni][r]);
      mx = fmaxf(mx, __shfl_xor(mx, 16));
      mx = fmaxf(mx, __shfl_xor(mx, 32));
      float mn = fmaxf(m_run[ni], mx);
      float corr = __expf(m_run[ni] - mn);
      float sum = 0.f;
      const int q = ni * 16 + l15;
      const int rbase = q * 128, sw = (q & 7) << 4;
#pragma unroll
      for (int mi = 0; mi < 4; ++mi) {
        u16x4 pk;
#pragma unroll
        for (int r = 0; r < 4; ++r) {
          float e = __expf(st[mi][ni][r] - mn);
          sum += e;
          pk[r] = f2bf(e);
        }
        // P[q][s], s = mi*16+g*4+r contiguous -> 8B swizzled store
        *(u16x4*)(Ps + ((rbase + (mi * 16 + g * 4) * 2) ^ sw)) = pk;
      }
      sum += __shfl_xor(sum, 16);
      sum += __shfl_xor(sum, 32);
      l_run[ni] = l_run[ni] * corr + sum;
      m_run[ni] = mn;
      corr_s[ni] = corr;
    }

    // rescale O^T — col q matches lane, zero shuffles
#pragma unroll
    for (int nd = 0; nd < 4; ++nd)
#pragma unroll
      for (int ni = 0; ni < 2; ++ni)
#pragma unroll
        for (int r = 0; r < 4; ++r)
          acc[nd][ni][r] *= corr_s[ni];

    // PV: O^T[d][q] += V^T[d][s] · P[q][s]
#pragma unroll
    for (int kk = 0; kk < 2; ++kk) {
      bf16x8 vf[4], pa[2];
#pragma unroll
      for (int nd = 0; nd < 4; ++nd) {
        int row = nd * 16 + l15;
        int off = (row * 128 + kk * 64 + g * 16) ^ ((row & 7) << 4);
        vf[nd] = *(const bf16x8*)(Vc + off);
      }
#pragma unroll
      for (int ni = 0; ni < 2; ++ni) {
        int q = ni * 16 + l15;
        int off = (q * 128 + kk * 64 + g * 16) ^ ((q & 7) << 4);
        pa[ni] = *(const bf16x8*)(Ps + off);
      }
#pragma unroll
      for (int nd = 0; nd < 4; ++nd)
#pragma unroll
        for (int ni = 0; ni < 2; ++ni)
          acc[nd][ni] = MFMA16(vf[nd], pa[ni], acc[nd][ni], 0, 0, 0);
    }

    asm volatile("s_waitcnt vmcnt(0)" ::: "memory");  // next stage landed
    __syncthreads();                                   // single barrier/chunk
  }

  // finalize: divide by l (per-lane), write concat [B,S,D] bf16
  const int b = bh >> 4, h = bh & 15;
  float invl[2] = {1.f / l_run[0], 1.f / l_run[1]};
#pragma unroll
  for (int ni = 0; ni < 2; ++ni) {
    int q = qt * 128 + w * 32 + ni * 16 + l15;
    size_t rowb = (size_t)(b * 1024 + q) * 1024 + h * 64;
#pragma unroll
    for (int nd = 0; nd < 4; ++nd) {
      u16x4 o;
#pragma unroll
      for (int r = 0; r < 4; ++r) o[r] = f2bf(acc[nd][ni][r] * invl[ni]);
      *(u16x4*)(Cc + rowb + nd * 16 + g * 4) = o;     // d = nd*16+g*4+r
    }
  }
}

// ---------------- launch ----------------
extern "C" void kernel_launch(void* const* d_in, const int* in_sizes, int n_in,
                              void* d_out, int out_size, void* d_ws, size_t ws_size,
                              hipStream_t stream) {
  const float* x  = (const float*)d_in[0];
  const float* Wq = (const float*)d_in[1];
  const float* Wk = (const float*)d_in[2];
  const float* Wv = (const float*)d_in[3];
  const float* bq = (const float*)d_in[4];
  const float* bk = (const float*)d_in[5];
  const float* bv = (const float*)d_in[6];
  const float* Wo = (const float*)d_in[7];
  const float* bo = (const float*)d_in[8];

  char* ws = (char*)d_ws;
  unsigned short* xb   = (unsigned short*)(ws);               // 16 MB (dead after gemm<0>)
  unsigned short* wqkv = (unsigned short*)(ws + 16777216);    //  6 MB [3][1024][1024]
  unsigned short* wob  = (unsigned short*)(ws + 23068672);    //  2 MB
  unsigned short* Qb   = (unsigned short*)(ws + 25165824);    // 16 MB [B,H,S,64]
  unsigned short* Kb   = (unsigned short*)(ws + 41943040);    // 16 MB [B,H,S,64]
  unsigned short* VtG  = (unsigned short*)(ws + 58720256);    // 16 MB [B*H,64,1024] (V^T)
  unsigned short* Cc   = xb;   // alias: xb dead after gemm<0>; peak ws = 75.5 MB

  cast_all<<<dim3(12288), dim3(256), 0, stream>>>(x, Wq, Wk, Wv, Wo, xb, wqkv, wob);
  gemm128<0><<<dim3(24, 64), dim3(256), 0, stream>>>(
      xb, wqkv, nullptr, nullptr, Qb, Kb, VtG, bq, bk, bv);
  attn_fused<<<dim3(1024), dim3(256), 0, stream>>>(Qb, Kb, VtG, Cc);
  gemm128<1><<<dim3(8, 64), dim3(256), 0, stream>>>(
      Cc, wob, (float*)d_out, bo, nullptr, nullptr, nullptr, nullptr, nullptr, nullptr);
}

// Round 6
// 252.612 us; speedup vs baseline: 1.1428x; 1.0122x over previous
//
#include <hip/hip_runtime.h>
#include <stdint.h>
#include <stddef.h>

// ---------------------------------------------------------------------------
// MultiHeadAttention: B=8 S=1024 D=1024 H=16 HD=64  (fp32 in/out, bf16 MFMA)
// R6: GEMMs converted to early-issue double-buffered pipeline (attn-proven
// structure, 1 barrier/K-step, loads in flight across compute phase) +
// bijective XCD swizzle on the QKV GEMM for A-panel L2 locality.
// ---------------------------------------------------------------------------

typedef short bf16x8 __attribute__((ext_vector_type(8)));   // 8 bf16 = 4 VGPR
typedef float f32x4  __attribute__((ext_vector_type(4)));
typedef unsigned short u16x8 __attribute__((ext_vector_type(8)));
typedef unsigned short u16x4 __attribute__((ext_vector_type(4)));

#define MFMA16 __builtin_amdgcn_mfma_f32_16x16x32_bf16

typedef const void __attribute__((address_space(1)))* gas1_t;
typedef void __attribute__((address_space(3)))* las3_t;

static __device__ __forceinline__ void gload16(const void* g, void* l) {
  // async global->LDS, 16B/lane, dest = wave-uniform base + lane*16
  __builtin_amdgcn_global_load_lds((gas1_t)g, (las3_t)l, 16, 0, 0);
}

static __device__ __forceinline__ unsigned short f2bf(float f) {
  union { float f; unsigned int u; } v; v.f = f;
  unsigned int r = v.u + 0x7fffu + ((v.u >> 16) & 1u);   // RNE
  return (unsigned short)(r >> 16);
}

// ---------------- cast inputs to bf16 ----------------
__global__ __launch_bounds__(256) void cast_all(
    const float* __restrict__ x, const float* __restrict__ Wq,
    const float* __restrict__ Wk, const float* __restrict__ Wv,
    const float* __restrict__ Wo,
    unsigned short* __restrict__ xb, unsigned short* __restrict__ wqkv,
    unsigned short* __restrict__ wob) {
  int base = (blockIdx.x * 256 + threadIdx.x) * 4;
  const float* s; unsigned short* d;
  if (base < 8388608) { s = x + base; d = xb + base; }
  else if (base < 11534336) {
    int o = base - 8388608; int wi = o >> 20;
    const float* w = (wi == 0) ? Wq : (wi == 1) ? Wk : Wv;
    s = w + (o & 1048575); d = wqkv + o;
  } else {
    int o = base - 11534336; s = Wo + o; d = wob + o;
  }
  float4 f = *(const float4*)s;
  u16x4 r; r[0] = f2bf(f.x); r[1] = f2bf(f.y); r[2] = f2bf(f.z); r[3] = f2bf(f.w);
  *(u16x4*)d = r;
}

// ---------------- 128x128 bf16 GEMM, C = A * B^T, K=1024 ----------------
// Double-buffered early-issue pipeline: stage(ks+1) issued before compute(ks);
// single vmcnt(0)+barrier per K-step at the bottom (loads land under compute).
// EPI 0: scatter Q/K -> [B,H,S,64] bf16 (+bias, Q scaled 0.125); V -> V^T
//        [B*H, 64 hd, 1024 s] bf16 (+bias) with packed u16x4 stores.
// EPI 1: f32 out + bias -> Cf
// SWZ: bijective XCD remap (nwg % 8 == 0): each XCD gets a contiguous run of
//      tiles (same brow stripe, marching bcol) -> A-panel stays in its L2.
template <int EPI, int NBX, bool SWZ>
__global__ __launch_bounds__(256) void gemm128(
    const unsigned short* __restrict__ A, const unsigned short* __restrict__ Bm,
    float* __restrict__ Cf, const float* __restrict__ bO,
    unsigned short* __restrict__ Qo, unsigned short* __restrict__ Ko,
    unsigned short* __restrict__ Vo,
    const float* __restrict__ bq, const float* __restrict__ bk,
    const float* __restrict__ bv) {
  __shared__ __align__(16) char sm[65536];        // 2 x (As 16K + Bs 16K)
  const int tid = threadIdx.x, lane = tid & 63, w = tid >> 6;
  const int wr = w >> 1, wc = w & 1;
  int i = blockIdx.x, j;
  if constexpr (SWZ) j = (i & 7) * (NBX * 64 / 8) + (i >> 3);
  else j = i;
  const int bcol = (j % NBX) * 128, brow = (j / NBX) * 128;
  const int l15 = lane & 15, g = lane >> 4;

  auto stage = [&](int ks, int buf) {
    char* Ad = sm + buf * 32768;
    char* Bd = Ad + 16384;
#pragma unroll
    for (int jj = 0; jj < 4; ++jj) {
      int p = (w * 4 + jj) * 1024 + lane * 16;    // physical LDS byte this lane fills
      int row = p >> 7;                           // 128B per row
      int cl = (lane & 7) ^ (row & 7);            // pre-swizzled source (rule #21)
      gload16(A + (size_t)(brow + row) * 1024 + ks * 64 + cl * 8,
              Ad + (w * 4 + jj) * 1024);
      gload16(Bm + (size_t)(bcol + row) * 1024 + ks * 64 + cl * 8,
              Bd + (w * 4 + jj) * 1024);
    }
  };

  stage(0, 0);
  asm volatile("s_waitcnt vmcnt(0)" ::: "memory");
  __syncthreads();

  f32x4 acc[4][4] = {};
  for (int ks = 0; ks < 16; ++ks) {
    const int cur = ks & 1;
    if (ks < 15) stage(ks + 1, cur ^ 1);          // early issue; drains at bottom
    const char* As = sm + cur * 32768;
    const char* Bs = As + 16384;
#pragma unroll
    for (int kk = 0; kk < 2; ++kk) {
      bf16x8 af[4], bfr[4];
#pragma unroll
      for (int mi = 0; mi < 4; ++mi) {
        int row = wr * 64 + mi * 16 + l15;
        int off = (row * 128 + kk * 64 + g * 16) ^ ((row & 7) << 4);
        af[mi] = *(const bf16x8*)(As + off);
      }
#pragma unroll
      for (int ni = 0; ni < 4; ++ni) {
        int row = wc * 64 + ni * 16 + l15;
        int off = (row * 128 + kk * 64 + g * 16) ^ ((row & 7) << 4);
        bfr[ni] = *(const bf16x8*)(Bs + off);
      }
#pragma unroll
      for (int mi = 0; mi < 4; ++mi)
#pragma unroll
        for (int ni = 0; ni < 4; ++ni)
          acc[mi][ni] = MFMA16(af[mi], bfr[ni], acc[mi][ni], 0, 0, 0);
    }
    asm volatile("s_waitcnt vmcnt(0)" ::: "memory");  // next tile landed
    __syncthreads();                                   // single barrier/K-step
  }
  // epilogue: C/D frag mapping col=lane&15, row=(lane>>4)*4+reg (m89-verified)
  if constexpr (EPI == 0) {
    const int b = brow >> 10;                     // 128 | 1024 -> constant per block
#pragma unroll
    for (int ni = 0; ni < 4; ++ni) {
      int n = bcol + wc * 64 + ni * 16 + l15;
      int t = n >> 10, nh = n & 1023;             // t wave-uniform (16-wide n span)
      int h = nh >> 6, hd = nh & 63;
      const float* bias = (t == 0) ? bq : (t == 1) ? bk : bv;
      float bb = bias[nh];
      if (t == 2) {
        // V^T: [(b*16+h)*64 + hd][1024 s], 4 consecutive s -> one 8B store
        size_t vtb = ((size_t)(b * 16 + h) * 64 + hd) * 1024;
#pragma unroll
        for (int mi = 0; mi < 4; ++mi) {
          int m0 = brow + wr * 64 + mi * 16 + g * 4;
          int srow0 = m0 & 1023;
          u16x4 vv;
#pragma unroll
          for (int r = 0; r < 4; ++r) vv[r] = f2bf(acc[mi][ni][r] + bb);
          *(u16x4*)(Vo + vtb + srow0) = vv;
        }
      } else {
        float scale = (t == 0) ? 0.125f : 1.0f;   // fold 1/sqrt(HD) into Q
        unsigned short* dst = (t == 0) ? Qo : Ko;
        size_t basei = ((size_t)(b * 16 + h) * 1024) * 64 + hd;
#pragma unroll
        for (int mi = 0; mi < 4; ++mi)
#pragma unroll
          for (int r = 0; r < 4; ++r) {
            int m = brow + wr * 64 + mi * 16 + g * 4 + r;
            int srow = m & 1023;
            dst[basei + (size_t)srow * 64] = f2bf((acc[mi][ni][r] + bb) * scale);
          }
      }
    }
  } else {
#pragma unroll
    for (int ni = 0; ni < 4; ++ni) {
      int n = bcol + wc * 64 + ni * 16 + l15;
      float bb = bO[n];
#pragma unroll
      for (int mi = 0; mi < 4; ++mi)
#pragma unroll
        for (int r = 0; r < 4; ++r) {
          int m = brow + wr * 64 + mi * 16 + g * 4 + r;
          Cf[(size_t)m * 1024 + n] = acc[mi][ni][r] + bb;
        }
    }
  }
}

// ---------------- fused flash attention (O^T orientation) ----------------
// 1-D grid 1024: id = qt*128 + bh  ->  all 8 q-tiles of head bh share id%8
// (same XCD L2 under round-robin dispatch). 256 thr = 4 waves, 32 q/wave.
// S^T = mfma(K, Q): lane holds col q = ni*16+l15, rows k.
// O^T = mfma(V^T, P): col q again -> corr/invl apply per-lane, NO shuffles.
__global__ __launch_bounds__(256, 3) void attn_fused(
    const unsigned short* __restrict__ Qb, const unsigned short* __restrict__ Kb,
    const unsigned short* __restrict__ VtG, unsigned short* __restrict__ Cc) {
  __shared__ __align__(16) char sm[49152];
  char* Ks = sm;                    // 2 x [64 s][64 d] bf16, XOR-swizzled (16K)
  char* Vt = sm + 16384;            // 2 x [64 d][64 s] bf16, XOR-swizzled (16K)
  const int tid = threadIdx.x, lane = tid & 63, w = tid >> 6;
  char* Ps = sm + 32768 + w * 4096; // per-wave [32 q][64 s] bf16, XOR-swizzled
  const int l15 = lane & 15, g = lane >> 4;
  const int id = blockIdx.x;
  const int qt = id >> 7, bh = id & 127;          // head-locality decode
  const size_t hb = (size_t)bh * (1024 * 64);

  // Q fragments straight to registers (B-operand rows q, d-contiguous)
  bf16x8 qreg[2][2];                               // [kk][ni]
#pragma unroll
  for (int kk = 0; kk < 2; ++kk)
#pragma unroll
    for (int ni = 0; ni < 2; ++ni) {
      int q = qt * 128 + w * 32 + ni * 16 + l15;
      qreg[kk][ni] = *(const bf16x8*)(Qb + hb + (size_t)q * 64 + kk * 32 + g * 8);
    }

  auto stage = [&](int c, int buf) {
#pragma unroll
    for (int j = 0; j < 2; ++j) {
      int p = (w * 2 + j) * 1024 + lane * 16;     // linear LDS byte this lane fills
      int row = p >> 7;
      int cl = (lane & 7) ^ (row & 7);            // pre-swizzled source (rule #21)
      gload16(Kb + hb + (size_t)(c * 64 + row) * 64 + cl * 8,
              Ks + buf * 8192 + (w * 2 + j) * 1024);
      gload16(VtG + hb + (size_t)row * 1024 + c * 64 + cl * 8,
              Vt + buf * 8192 + (w * 2 + j) * 1024);
    }
  };

  stage(0, 0);
  asm volatile("s_waitcnt vmcnt(0)" ::: "memory");
  __syncthreads();

  f32x4 acc[4][2] = {};                            // O^T [nd: d-frag][ni: q-frag]
  float m_run[2] = {-1e30f, -1e30f};
  float l_run[2] = {0.f, 0.f};

  for (int c = 0; c < 16; ++c) {
    const int cur = c & 1;
    if (c < 15) stage(c + 1, cur ^ 1);             // early issue; drains at bottom
    const char* Kc = Ks + cur * 8192;
    const char* Vc = Vt + cur * 8192;

    // S^T[k][q] = K · Q^T
    f32x4 st[4][2] = {};
#pragma unroll
    for (int kk = 0; kk < 2; ++kk) {
      bf16x8 ka[4];
#pragma unroll
      for (int mi = 0; mi < 4; ++mi) {
        int row = mi * 16 + l15;
        int off = (row * 128 + kk * 64 + g * 16) ^ ((row & 7) << 4);
        ka[mi] = *(const bf16x8*)(Kc + off);
      }
#pragma unroll
      for (int mi = 0; mi < 4; ++mi)
#pragma unroll
        for (int ni = 0; ni < 2; ++ni)
          st[mi][ni] = MFMA16(ka[mi], qreg[kk][ni], st[mi][ni], 0, 0, 0);
    }

    // online softmax: lane holds 16 of 64 k for q = ni*16+l15 (4 g-lanes/q)
    float corr_s[2];
#pragma unroll
    for (int ni = 0; ni < 2; ++ni) {
      float mx = -1e30f;
#pragma unroll
      for (int mi = 0; mi < 4; ++mi)
#pragma unroll
        for (int r = 0; r < 4; ++r) mx = fmaxf(mx, st[mi][ni][r]);
      mx = fmaxf(mx, __shfl_xor(mx, 16));
      mx = fmaxf(mx, __shfl_xor(mx, 32));
      float mn = fmaxf(m_run[ni], mx);
      float corr = __expf(m_run[ni] - mn);
      float sum = 0.f;
      const int q = ni * 16 + l15;
      const int rbase = q * 128, sw = (q & 7) << 4;
#pragma unroll
      for (int mi = 0; mi < 4; ++mi) {
        u16x4 pk;
#pragma unroll
        for (int r = 0; r < 4; ++r) {
          float e = __expf(st[mi][ni][r] - mn);
          sum += e;
          pk[r] = f2bf(e);
        }
        // P[q][s], s = mi*16+g*4+r contiguous -> 8B swizzled store
        *(u16x4*)(Ps + ((rbase + (mi * 16 + g * 4) * 2) ^ sw)) = pk;
      }
      sum += __shfl_xor(sum, 16);
      sum += __shfl_xor(sum, 32);
      l_run[ni] = l_run[ni] * corr + sum;
      m_run[ni] = mn;
      corr_s[ni] = corr;
    }

    // rescale O^T — col q matches lane, zero shuffles
#pragma unroll
    for (int nd = 0; nd < 4; ++nd)
#pragma unroll
      for (int ni = 0; ni < 2; ++ni)
#pragma unroll
        for (int r = 0; r < 4; ++r)
          acc[nd][ni][r] *= corr_s[ni];

    // PV: O^T[d][q] += V^T[d][s] · P[q][s]
#pragma unroll
    for (int kk = 0; kk < 2; ++kk) {
      bf16x8 vf[4], pa[2];
#pragma unroll
      for (int nd = 0; nd < 4; ++nd) {
        int row = nd * 16 + l15;
        int off = (row * 128 + kk * 64 + g * 16) ^ ((row & 7) << 4);
        vf[nd] = *(const bf16x8*)(Vc + off);
      }
#pragma unroll
      for (int ni = 0; ni < 2; ++ni) {
        int q = ni * 16 + l15;
        int off = (q * 128 + kk * 64 + g * 16) ^ ((q & 7) << 4);
        pa[ni] = *(const bf16x8*)(Ps + off);
      }
#pragma unroll
      for (int nd = 0; nd < 4; ++nd)
#pragma unroll
        for (int ni = 0; ni < 2; ++ni)
          acc[nd][ni] = MFMA16(vf[nd], pa[ni], acc[nd][ni], 0, 0, 0);
    }

    asm volatile("s_waitcnt vmcnt(0)" ::: "memory");  // next stage landed
    __syncthreads();                                   // single barrier/chunk
  }

  // finalize: divide by l (per-lane), write concat [B,S,D] bf16
  const int b = bh >> 4, h = bh & 15;
  float invl[2] = {1.f / l_run[0], 1.f / l_run[1]};
#pragma unroll
  for (int ni = 0; ni < 2; ++ni) {
    int q = qt * 128 + w * 32 + ni * 16 + l15;
    size_t rowb = (size_t)(b * 1024 + q) * 1024 + h * 64;
#pragma unroll
    for (int nd = 0; nd < 4; ++nd) {
      u16x4 o;
#pragma unroll
      for (int r = 0; r < 4; ++r) o[r] = f2bf(acc[nd][ni][r] * invl[ni]);
      *(u16x4*)(Cc + rowb + nd * 16 + g * 4) = o;     // d = nd*16+g*4+r
    }
  }
}

// ---------------- launch ----------------
extern "C" void kernel_launch(void* const* d_in, const int* in_sizes, int n_in,
                              void* d_out, int out_size, void* d_ws, size_t ws_size,
                              hipStream_t stream) {
  const float* x  = (const float*)d_in[0];
  const float* Wq = (const float*)d_in[1];
  const float* Wk = (const float*)d_in[2];
  const float* Wv = (const float*)d_in[3];
  const float* bq = (const float*)d_in[4];
  const float* bk = (const float*)d_in[5];
  const float* bv = (const float*)d_in[6];
  const float* Wo = (const float*)d_in[7];
  const float* bo = (const float*)d_in[8];

  char* ws = (char*)d_ws;
  unsigned short* xb   = (unsigned short*)(ws);               // 16 MB (dead after gemm<0>)
  unsigned short* wqkv = (unsigned short*)(ws + 16777216);    //  6 MB [3][1024][1024]
  unsigned short* wob  = (unsigned short*)(ws + 23068672);    //  2 MB
  unsigned short* Qb   = (unsigned short*)(ws + 25165824);    // 16 MB [B,H,S,64]
  unsigned short* Kb   = (unsigned short*)(ws + 41943040);    // 16 MB [B,H,S,64]
  unsigned short* VtG  = (unsigned short*)(ws + 58720256);    // 16 MB [B*H,64,1024] (V^T)
  unsigned short* Cc   = xb;   // alias: xb dead after gemm<0>; peak ws = 75.5 MB

  cast_all<<<dim3(12288), dim3(256), 0, stream>>>(x, Wq, Wk, Wv, Wo, xb, wqkv, wob);
  gemm128<0, 24, true><<<dim3(1536), dim3(256), 0, stream>>>(
      xb, wqkv, nullptr, nullptr, Qb, Kb, VtG, bq, bk, bv);
  attn_fused<<<dim3(1024), dim3(256), 0, stream>>>(Qb, Kb, VtG, Cc);
  gemm128<1, 8, false><<<dim3(512), dim3(256), 0, stream>>>(
      Cc, wob, (float*)d_out, bo, nullptr, nullptr, nullptr, nullptr, nullptr, nullptr);
}